// Round 6
// baseline (793.216 us; speedup 1.0000x reference)
//
#include <hip/hip_runtime.h>

#define NUSER 100000
#define NITEM 100000
#define NEDGE 1600000
#define HID 64
#define FCHUNK 4096

__device__ __forceinline__ float bf2f(unsigned short h) {
  unsigned int u = ((unsigned int)h) << 16;
  float f; __builtin_memcpy(&f, &u, 4); return f;
}
__device__ __forceinline__ unsigned short f2bf(float x) {
  unsigned int u; __builtin_memcpy(&u, &x, 4);
  u += 0x7fffu + ((u >> 16) & 1u);
  return (unsigned short)(u >> 16);
}
// unpack packed pair of bf16 (low ushort = channel ch, high = ch+1)
__device__ __forceinline__ float bflo(unsigned int u) {
  unsigned int v = u << 16; float f; __builtin_memcpy(&f, &v, 4); return f;
}
__device__ __forceinline__ float bfhi(unsigned int u) {
  unsigned int v = u & 0xffff0000u; float f; __builtin_memcpy(&f, &v, 4); return f;
}
__device__ __forceinline__ int xcd_id() {
  int x;
  asm volatile("s_getreg_b32 %0, hwreg(HW_REG_XCC_ID)" : "=s"(x));
  return x & 7;
}

// ---------------------------------------------------------------------------
// GEMM: C[M,64] = relu(A[M,K] @ W[K,64] + bias); 64x64 tile, 4x4/thread.
// ---------------------------------------------------------------------------
template<int K>
__global__ __launch_bounds__(256) void gemm64(
    const float* __restrict__ A, const float* __restrict__ W,
    const float* __restrict__ bias, float* __restrict__ C, int M)
{
  __shared__ float Ws[K * 64];
  __shared__ float As[64 * 68];
  const int tid = threadIdx.x;

  for (int i = tid; i < K * 16; i += 256)
    ((float4*)Ws)[i] = ((const float4*)W)[i];

  const int tx = tid & 15;
  const int ty = tid >> 4;
  float4 bv = ((const float4*)bias)[tx];

  const int ntiles = (M + 63) >> 6;
  for (int t = blockIdx.x; t < ntiles; t += gridDim.x) {
    const int row0 = t << 6;
    float acc[4][4] = {};
    for (int kb = 0; kb < K; kb += 64) {
      __syncthreads();
      for (int i = tid; i < 1024; i += 256) {
        int r = i >> 4;
        int kk = (i & 15) << 2;
        int gr = row0 + r; if (gr > M - 1) gr = M - 1;
        *(float4*)&As[r * 68 + kk] = *(const float4*)(A + (size_t)gr * K + kb + kk);
      }
      __syncthreads();
      #pragma unroll 8
      for (int k = 0; k < 64; ++k) {
        float4 w = *(const float4*)&Ws[(kb + k) * 64 + tx * 4];
        float a0 = As[(ty * 4 + 0) * 68 + k];
        float a1 = As[(ty * 4 + 1) * 68 + k];
        float a2 = As[(ty * 4 + 2) * 68 + k];
        float a3 = As[(ty * 4 + 3) * 68 + k];
        acc[0][0] += a0 * w.x; acc[0][1] += a0 * w.y; acc[0][2] += a0 * w.z; acc[0][3] += a0 * w.w;
        acc[1][0] += a1 * w.x; acc[1][1] += a1 * w.y; acc[1][2] += a1 * w.z; acc[1][3] += a1 * w.w;
        acc[2][0] += a2 * w.x; acc[2][1] += a2 * w.y; acc[2][2] += a2 * w.z; acc[2][3] += a2 * w.w;
        acc[3][0] += a3 * w.x; acc[3][1] += a3 * w.y; acc[3][2] += a3 * w.z; acc[3][3] += a3 * w.w;
      }
    }
    #pragma unroll
    for (int r = 0; r < 4; ++r) {
      int gr = row0 + ty * 4 + r;
      if (gr < M) {
        float4 o = make_float4(fmaxf(acc[r][0] + bv.x, 0.f), fmaxf(acc[r][1] + bv.y, 0.f),
                               fmaxf(acc[r][2] + bv.z, 0.f), fmaxf(acc[r][3] + bv.w, 0.f));
        *(float4*)(C + (size_t)gr * 64 + tx * 4) = o;
      }
    }
  }
}

// ---------------------------------------------------------------------------
// Fused dual GEMM x2 (both node types in one dispatch, grid split):
//   Ga = bf16(A @ Wa) ; Tb = A @ Wb + bias.  Tb may alias A (row-wise safe:
//   rows staged to LDS before write, tiles disjoint).
// ---------------------------------------------------------------------------
__global__ __launch_bounds__(256) void gemm_dual2(
    const float* A0, const float* __restrict__ Wa0, const float* __restrict__ Wb0,
    const float* __restrict__ bias0, unsigned short* Ga0, float* Tb0,
    const float* A1, const float* __restrict__ Wa1, const float* __restrict__ Wb1,
    const float* __restrict__ bias1, unsigned short* Ga1, float* Tb1,
    int M, int half_blocks)
{
  __shared__ float Ws[64 * 128];
  __shared__ float As[64 * 68];
  const int tid = threadIdx.x;

  const float* A; const float* Wa; const float* Wb; const float* bias;
  unsigned short* Ga; float* Tb; int t;
  if ((int)blockIdx.x < half_blocks) {
    A = A0; Wa = Wa0; Wb = Wb0; bias = bias0; Ga = Ga0; Tb = Tb0; t = blockIdx.x;
  } else {
    A = A1; Wa = Wa1; Wb = Wb1; bias = bias1; Ga = Ga1; Tb = Tb1; t = blockIdx.x - half_blocks;
  }

  for (int i = tid; i < 2048; i += 256) {
    int k = i >> 5, cg = i & 31;
    float4 v = (cg < 16) ? ((const float4*)Wa)[k * 16 + cg]
                         : ((const float4*)Wb)[k * 16 + (cg - 16)];
    ((float4*)Ws)[k * 32 + cg] = v;
  }

  const int tx = tid & 15;
  const int ty = tid >> 4;
  float4 bvB = ((const float4*)bias)[tx];

  const int row0 = t << 6;
  float accA[4][4] = {};
  float accB[4][4] = {};
  __syncthreads();
  for (int i = tid; i < 1024; i += 256) {
    int r = i >> 4;
    int kk = (i & 15) << 2;
    int gr = row0 + r; if (gr > M - 1) gr = M - 1;
    *(float4*)&As[r * 68 + kk] = *(const float4*)(A + (size_t)gr * 64 + kk);
  }
  __syncthreads();
  #pragma unroll 8
  for (int k = 0; k < 64; ++k) {
    float4 wa = *(const float4*)&Ws[k * 128 + tx * 4];
    float4 wb = *(const float4*)&Ws[k * 128 + 64 + tx * 4];
    float a0 = As[(ty * 4 + 0) * 68 + k];
    float a1 = As[(ty * 4 + 1) * 68 + k];
    float a2 = As[(ty * 4 + 2) * 68 + k];
    float a3 = As[(ty * 4 + 3) * 68 + k];
    accA[0][0] += a0 * wa.x; accA[0][1] += a0 * wa.y; accA[0][2] += a0 * wa.z; accA[0][3] += a0 * wa.w;
    accA[1][0] += a1 * wa.x; accA[1][1] += a1 * wa.y; accA[1][2] += a1 * wa.z; accA[1][3] += a1 * wa.w;
    accA[2][0] += a2 * wa.x; accA[2][1] += a2 * wa.y; accA[2][2] += a2 * wa.z; accA[2][3] += a2 * wa.w;
    accA[3][0] += a3 * wa.x; accA[3][1] += a3 * wa.y; accA[3][2] += a3 * wa.z; accA[3][3] += a3 * wa.w;
    accB[0][0] += a0 * wb.x; accB[0][1] += a0 * wb.y; accB[0][2] += a0 * wb.z; accB[0][3] += a0 * wb.w;
    accB[1][0] += a1 * wb.x; accB[1][1] += a1 * wb.y; accB[1][2] += a1 * wb.z; accB[1][3] += a1 * wb.w;
    accB[2][0] += a2 * wb.x; accB[2][1] += a2 * wb.y; accB[2][2] += a2 * wb.z; accB[2][3] += a2 * wb.w;
    accB[3][0] += a3 * wb.x; accB[3][1] += a3 * wb.y; accB[3][2] += a3 * wb.z; accB[3][3] += a3 * wb.w;
  }
  #pragma unroll
  for (int r = 0; r < 4; ++r) {
    int gr = row0 + ty * 4 + r;
    if (gr < M) {
      ushort4 g;
      g.x = f2bf(accA[r][0]); g.y = f2bf(accA[r][1]);
      g.z = f2bf(accA[r][2]); g.w = f2bf(accA[r][3]);
      *(ushort4*)(Ga + (size_t)gr * 64 + tx * 4) = g;
      *(float4*)(Tb + (size_t)gr * 64 + tx * 4) =
          make_float4(accB[r][0] + bvB.x, accB[r][1] + bvB.y,
                      accB[r][2] + bvB.z, accB[r][3] + bvB.w);
    }
  }
}

// ---------------------------------------------------------------------------
// Fused aggregation x2: out[n,:] = relu(mean_{j in N(n)} bf16 G[j,:] + T[n,:])
// 2 nodes per wave, 2 channels per lane (32-bit gathers). idx stream read
// non-temporally (read-once; keep L2 for the reused G rows).
// ---------------------------------------------------------------------------
__global__ __launch_bounds__(256) void agg2(
    const unsigned short* __restrict__ G0, const float* T0,
    const int* __restrict__ ptr0, const int* __restrict__ idx0, float* out0,
    const unsigned short* __restrict__ G1, const float* T1,
    const int* __restrict__ ptr1, const int* __restrict__ idx1, float* out1,
    int n_dst)
{
  const int lane = threadIdx.x & 63;
  const int sub = lane >> 5;            // which node of the wave's pair
  const int ch = (lane & 31) << 1;      // channel base (2 channels/lane)
  int wave = blockIdx.x * 4 + (threadIdx.x >> 6);
  const int nwh = (gridDim.x * 4) >> 1; // waves per side
  const unsigned short* G; const float* T; const int* ptr; const int* idx; float* out;
  if (wave < nwh) { G = G0; T = T0; ptr = ptr0; idx = idx0; out = out0; }
  else { G = G1; T = T1; ptr = ptr1; idx = idx1; out = out1; wave -= nwh; }

  for (int n0 = wave * 2; n0 < n_dst; n0 += nwh * 2) {
    const int n = n0 + sub;
    const bool valid = n < n_dst;
    const int s = valid ? ptr[n] : 0;
    const int e = valid ? ptr[n + 1] : 0;
    float2 t = make_float2(0.f, 0.f);
    if (valid) t = *(const float2*)(T + (size_t)n * 64 + ch);
    float l0 = 0.f, h0 = 0.f, l1 = 0.f, h1 = 0.f;
    float l2 = 0.f, h2 = 0.f, l3 = 0.f, h3 = 0.f;
    float l4 = 0.f, h4 = 0.f, l5 = 0.f, h5 = 0.f;
    float l6 = 0.f, h6 = 0.f, l7 = 0.f, h7 = 0.f;
    int i = s;
    for (; i + 8 <= e; i += 8) {
      int j0 = __builtin_nontemporal_load(idx + i + 0);
      int j1 = __builtin_nontemporal_load(idx + i + 1);
      int j2 = __builtin_nontemporal_load(idx + i + 2);
      int j3 = __builtin_nontemporal_load(idx + i + 3);
      int j4 = __builtin_nontemporal_load(idx + i + 4);
      int j5 = __builtin_nontemporal_load(idx + i + 5);
      int j6 = __builtin_nontemporal_load(idx + i + 6);
      int j7 = __builtin_nontemporal_load(idx + i + 7);
      unsigned int g0 = *(const unsigned int*)(G + (size_t)j0 * 64 + ch);
      unsigned int g1 = *(const unsigned int*)(G + (size_t)j1 * 64 + ch);
      unsigned int g2 = *(const unsigned int*)(G + (size_t)j2 * 64 + ch);
      unsigned int g3 = *(const unsigned int*)(G + (size_t)j3 * 64 + ch);
      unsigned int g4 = *(const unsigned int*)(G + (size_t)j4 * 64 + ch);
      unsigned int g5 = *(const unsigned int*)(G + (size_t)j5 * 64 + ch);
      unsigned int g6 = *(const unsigned int*)(G + (size_t)j6 * 64 + ch);
      unsigned int g7 = *(const unsigned int*)(G + (size_t)j7 * 64 + ch);
      l0 += bflo(g0); h0 += bfhi(g0); l1 += bflo(g1); h1 += bfhi(g1);
      l2 += bflo(g2); h2 += bfhi(g2); l3 += bflo(g3); h3 += bfhi(g3);
      l4 += bflo(g4); h4 += bfhi(g4); l5 += bflo(g5); h5 += bfhi(g5);
      l6 += bflo(g6); h6 += bfhi(g6); l7 += bflo(g7); h7 += bfhi(g7);
    }
    for (; i < e; ++i) {
      int j = __builtin_nontemporal_load(idx + i);
      unsigned int g = *(const unsigned int*)(G + (size_t)j * 64 + ch);
      l0 += bflo(g); h0 += bfhi(g);
    }
    float sl = ((l0 + l1) + (l2 + l3)) + ((l4 + l5) + (l6 + l7));
    float sh = ((h0 + h1) + (h2 + h3)) + ((h4 + h5) + (h6 + h7));
    int deg = e - s;
    float inv = 1.f / (float)(deg > 0 ? deg : 1);
    if (valid) {
      float2 o = make_float2(fmaxf(sl * inv + t.x, 0.f), fmaxf(sh * inv + t.y, 0.f));
      *(float2*)(out + (size_t)n * 64 + ch) = o;
    }
  }
}

// ---------------------------------------------------------------------------
// CSR build (both edge types fused per pass)
// ---------------------------------------------------------------------------
__global__ void count2(const int* __restrict__ dstA, const int* __restrict__ dstB,
                       int* cntA, int* cntB, int E) {
  int e = blockIdx.x * 256 + threadIdx.x;
  if (e < E) atomicAdd(&cntA[__builtin_nontemporal_load(dstA + e)], 1);
  else { e -= E; if (e < E) atomicAdd(&cntB[__builtin_nontemporal_load(dstB + e)], 1); }
}

__global__ void scan1_2(const int* __restrict__ cntA, int* partA,
                        const int* __restrict__ cntB, int* partB, int n, int nbh) {
  __shared__ int sdata[256];
  const int* cnt; int* part; int b;
  if ((int)blockIdx.x < nbh) { cnt = cntA; part = partA; b = blockIdx.x; }
  else { cnt = cntB; part = partB; b = blockIdx.x - nbh; }
  int base = b * 1024 + threadIdx.x * 4;
  int s = 0;
  #pragma unroll
  for (int j = 0; j < 4; ++j) { int i = base + j; if (i < n) s += cnt[i]; }
  sdata[threadIdx.x] = s; __syncthreads();
  for (int off = 128; off > 0; off >>= 1) {
    if ((int)threadIdx.x < off) sdata[threadIdx.x] += sdata[threadIdx.x + off];
    __syncthreads();
  }
  if (threadIdx.x == 0) part[b] = sdata[0];
}

__global__ void scan2_2(int* partA, int* totalA, int* partB, int* totalB, int nb) {
  __shared__ int sdata[256];
  int* part = blockIdx.x ? partB : partA;
  int* total = blockIdx.x ? totalB : totalA;
  if ((int)threadIdx.x < nb) sdata[threadIdx.x] = part[threadIdx.x];
  __syncthreads();
  if (threadIdx.x == 0) {
    int run = 0;
    for (int b = 0; b < nb; ++b) { int t = sdata[b]; sdata[b] = run; run += t; }
    *total = run;
  }
  __syncthreads();
  if ((int)threadIdx.x < nb) part[threadIdx.x] = sdata[threadIdx.x];
}

__global__ void scan3_2(const int* __restrict__ cntA, const int* __restrict__ partA,
                        int* ptrA, int* curA,
                        const int* __restrict__ cntB, const int* __restrict__ partB,
                        int* ptrB, int* curB, int n, int nbh) {
  __shared__ int sdata[256];
  const int* cnt; const int* part; int* ptr; int* cursor; int b;
  if ((int)blockIdx.x < nbh) { cnt = cntA; part = partA; ptr = ptrA; cursor = curA; b = blockIdx.x; }
  else { cnt = cntB; part = partB; ptr = ptrB; cursor = curB; b = blockIdx.x - nbh; }
  int base = b * 1024 + threadIdx.x * 4;
  int v[4];
  #pragma unroll
  for (int j = 0; j < 4; ++j) { int i = base + j; v[j] = (i < n) ? cnt[i] : 0; }
  int ts = v[0] + v[1] + v[2] + v[3];
  sdata[threadIdx.x] = ts; __syncthreads();
  for (int off = 1; off < 256; off <<= 1) {
    int x = 0;
    if ((int)threadIdx.x >= off) x = sdata[threadIdx.x - off];
    __syncthreads();
    if ((int)threadIdx.x >= off) sdata[threadIdx.x] += x;
    __syncthreads();
  }
  int run = sdata[threadIdx.x] - ts + part[b];
  #pragma unroll
  for (int j = 0; j < 4; ++j) {
    int i = base + j;
    if (i < n) { ptr[i] = run; cursor[i] = run; }
    run += v[j];
  }
}

// Fill with TRUE XCD slicing + non-temporal streaming reads. Each block reads
// its hardware XCC_ID and only scatters edges whose dst falls in its XCD's
// node slice -> every idx/cursor line is written by exactly one XCD. The
// dst/src streams are nt-loads so they do NOT evict the XCD's dirty idx
// working set (~1.7 MB, fits 4 MiB L2) -> lines fill completely, evict once.
// Coverage despite undefined block->XCD mapping: per-XCD work-stealing.
__global__ __launch_bounds__(256) void fill2(
    const int* __restrict__ srcA, const int* __restrict__ dstA, int* curA, int* __restrict__ idxA,
    const int* __restrict__ srcB, const int* __restrict__ dstB, int* curB, int* __restrict__ idxB,
    int* wc, int E, int npg)
{
  const int g = xcd_id();
  const int lo = g * npg, hi = lo + npg;
  const int nchunk = (E + FCHUNK - 1) / FCHUNK;   // per edge type
  __shared__ int s_c;
  for (;;) {
    if (threadIdx.x == 0) s_c = atomicAdd(&wc[g * 32], 1);
    __syncthreads();
    const int c = s_c;
    __syncthreads();
    if (c >= 2 * nchunk) break;
    const int half = c >= nchunk ? 1 : 0;
    const int cc = half ? c - nchunk : c;
    const int* src = half ? srcB : srcA;
    const int* dst = half ? dstB : dstA;
    int* cursor = half ? curB : curA;
    int* idx = half ? idxB : idxA;
    const int e0 = cc * FCHUNK;
    const int e1 = min(e0 + FCHUNK, E);
    for (int e = e0 + (int)threadIdx.x; e < e1; e += 256) {
      int d = __builtin_nontemporal_load(dst + e);
      if (d >= lo && d < hi) {
        int sv = __builtin_nontemporal_load(src + e);
        int p = atomicAdd(&cursor[d], 1);
        idx[p] = sv;
      }
    }
  }
}

// ---------------------------------------------------------------------------
extern "C" void kernel_launch(void* const* d_in, const int* in_sizes, int n_in,
                              void* d_out, int out_size, void* d_ws, size_t ws_size,
                              hipStream_t stream) {
  const float* x_user = (const float*)d_in[0];
  const float* x_item = (const float*)d_in[1];
  const int*   edge_ui = (const int*)d_in[2];
  const int*   edge_iu = (const int*)d_in[3];
  const float* Wu = (const float*)d_in[4];
  const float* bu = (const float*)d_in[5];
  const float* Wi = (const float*)d_in[6];
  const float* bi = (const float*)d_in[7];
  const float* Wl = (const float*)d_in[8];
  const float* bl = (const float*)d_in[9];
  const float* Wr = (const float*)d_in[10];

  float* outU = (float*)d_out;
  float* outI = outU + (size_t)NUSER * HID;

  char* p = (char*)d_ws;
  auto alloc = [&](size_t bytes) -> void* {
    void* r = (void*)p; p += (bytes + 255) & ~(size_t)255; return r;
  };
  float* U = (float*)alloc((size_t)NUSER * HID * 4);          // hu0
  float* I = (float*)alloc((size_t)NITEM * HID * 4);          // hi0
  unsigned short* GA = (unsigned short*)alloc((size_t)NUSER * HID * 2);
  unsigned short* GB = (unsigned short*)alloc((size_t)NITEM * HID * 2);
  // Single contiguous zeroed carve: cnt_ui | cnt_iu | work counters.
  // (r3 lesson: alloc() pads to 256B, so separate carves + one memset = UB.)
  int* cnt_ui = (int*)alloc(((size_t)NITEM + NUSER + 256) * 4);  // doubles as cursor
  int* cnt_iu = cnt_ui + NITEM;                                  // doubles as cursor
  int* wc     = cnt_ui + NITEM + NUSER;                          // 8 XCD counters (x32 pad)
  int* ptr_ui = (int*)alloc(((size_t)NITEM + 1) * 4);
  int* ptr_iu = (int*)alloc(((size_t)NUSER + 1) * 4);
  int* idx_ui = (int*)alloc((size_t)NEDGE * 4);
  int* idx_iu = (int*)alloc((size_t)NEDGE * 4);
  int* part_ui = (int*)alloc(512);
  int* part_iu = (int*)alloc(512);

  // ---- CSR build (5 dispatches + memset) ----
  hipMemsetAsync(cnt_ui, 0, (size_t)(NITEM + NUSER + 256) * 4, stream);
  count2<<<2 * (NEDGE / 256), 256, 0, stream>>>(edge_ui + NEDGE, edge_iu + NEDGE,
                                                cnt_ui, cnt_iu, NEDGE);
  const int NB = (NITEM + 1023) / 1024;  // 98
  scan1_2<<<2 * NB, 256, 0, stream>>>(cnt_ui, part_ui, cnt_iu, part_iu, NITEM, NB);
  scan2_2<<<2, 128, 0, stream>>>(part_ui, ptr_ui + NITEM, part_iu, ptr_iu + NUSER, NB);
  scan3_2<<<2 * NB, 256, 0, stream>>>(cnt_ui, part_ui, ptr_ui, cnt_ui,
                                      cnt_iu, part_iu, ptr_iu, cnt_iu, NITEM, NB);
  fill2<<<2048, 256, 0, stream>>>(edge_ui, edge_ui + NEDGE, cnt_ui, idx_ui,
                                  edge_iu, edge_iu + NEDGE, cnt_iu, idx_iu,
                                  wc, NEDGE, NITEM / 8);

  const int GT = (NUSER + 63) / 64;           // 1563
  const int AGG_B = 2 * ((NUSER / 2 + 3) / 4); // 25000 (2 nodes/wave, 2 sides)

  const float* Wl00 = Wl;             const float* Wl01 = Wl + 4096;
  const float* Wl10 = Wl + 2 * 4096;  const float* Wl11 = Wl + 3 * 4096;
  const float* Wr00 = Wr;             const float* Wr01 = Wr + 4096;
  const float* Wr10 = Wr + 2 * 4096;  const float* Wr11 = Wr + 3 * 4096;
  const float* bl00 = bl;             const float* bl01 = bl + 64;
  const float* bl10 = bl + 128;       const float* bl11 = bl + 192;

  // ---- input linears ----
  gemm64<128><<<GT, 256, 0, stream>>>(x_user, Wu, bu, U, NUSER);  // hu0
  gemm64<64 ><<<GT, 256, 0, stream>>>(x_item, Wi, bi, I, NITEM);  // hi0

  // ---- layer 0 ----
  // GA = bf16(hu0@Wl00) [items gather], outU = hu0@Wr01 + bl01 [users' T]
  // GB = bf16(hi0@Wl01) [users gather], outI = hi0@Wr00 + bl00 [items' T]
  gemm_dual2<<<2 * GT, 256, 0, stream>>>(U, Wl00, Wr01, bl01, GA, outU,
                                         I, Wl01, Wr00, bl00, GB, outI,
                                         NUSER, GT);
  // hi1 = relu(mean_ui(GA) + outI) -> outI ; hu1 = relu(mean_iu(GB) + outU) -> outU
  agg2<<<AGG_B, 256, 0, stream>>>(GA, outI, ptr_ui, idx_ui, outI,
                                  GB, outU, ptr_iu, idx_iu, outU, NITEM);

  // ---- layer 1 ----
  // GA = bf16(hi1@Wl11) [users gather], outI = hi1@Wr10 + bl10 (in-place)
  // GB = bf16(hu1@Wl10) [items gather], outU = hu1@Wr11 + bl11 (in-place)
  gemm_dual2<<<2 * GT, 256, 0, stream>>>(outI, Wl11, Wr10, bl10, GA, outI,
                                         outU, Wl10, Wr11, bl11, GB, outU,
                                         NITEM, GT);
  // final hu = relu(mean_iu(GA) + outU) ; final hi = relu(mean_ui(GB) + outI)
  agg2<<<AGG_B, 256, 0, stream>>>(GA, outU, ptr_iu, idx_iu, outU,
                                  GB, outI, ptr_ui, idx_ui, outI, NUSER);
}

// Round 7
// 609.176 us; speedup vs baseline: 1.3021x; 1.3021x over previous
//
#include <hip/hip_runtime.h>

#define NUSER 100000
#define NITEM 100000
#define NEDGE 1600000
#define HID 64
#define NPB 256                 // nodes per bucket (pow2: bucket = dst>>8)
#define NBKT 391                // ceil(100000/256)
#define ACHUNK 8192             // partition chunk (edges)
#define NCHUNK ((NEDGE + ACHUNK - 1) / ACHUNK)   // 196 per edge type

__device__ __forceinline__ unsigned short f2bf(float x) {
  unsigned int u; __builtin_memcpy(&u, &x, 4);
  u += 0x7fffu + ((u >> 16) & 1u);
  return (unsigned short)(u >> 16);
}
__device__ __forceinline__ float bflo(unsigned int u) {
  unsigned int v = u << 16; float f; __builtin_memcpy(&f, &v, 4); return f;
}
__device__ __forceinline__ float bfhi(unsigned int u) {
  unsigned int v = u & 0xffff0000u; float f; __builtin_memcpy(&f, &v, 4); return f;
}

// ---------------------------------------------------------------------------
// GEMM: C[M,64] = relu(A[M,K] @ W[K,64] + bias); 64x64 tile, 4x4/thread.
// ---------------------------------------------------------------------------
template<int K>
__global__ __launch_bounds__(256) void gemm64(
    const float* __restrict__ A, const float* __restrict__ W,
    const float* __restrict__ bias, float* __restrict__ C, int M)
{
  __shared__ float Ws[K * 64];
  __shared__ float As[64 * 68];
  const int tid = threadIdx.x;

  for (int i = tid; i < K * 16; i += 256)
    ((float4*)Ws)[i] = ((const float4*)W)[i];

  const int tx = tid & 15;
  const int ty = tid >> 4;
  float4 bv = ((const float4*)bias)[tx];

  const int ntiles = (M + 63) >> 6;
  for (int t = blockIdx.x; t < ntiles; t += gridDim.x) {
    const int row0 = t << 6;
    float acc[4][4] = {};
    for (int kb = 0; kb < K; kb += 64) {
      __syncthreads();
      for (int i = tid; i < 1024; i += 256) {
        int r = i >> 4;
        int kk = (i & 15) << 2;
        int gr = row0 + r; if (gr > M - 1) gr = M - 1;
        *(float4*)&As[r * 68 + kk] = *(const float4*)(A + (size_t)gr * K + kb + kk);
      }
      __syncthreads();
      #pragma unroll 8
      for (int k = 0; k < 64; ++k) {
        float4 w = *(const float4*)&Ws[(kb + k) * 64 + tx * 4];
        float a0 = As[(ty * 4 + 0) * 68 + k];
        float a1 = As[(ty * 4 + 1) * 68 + k];
        float a2 = As[(ty * 4 + 2) * 68 + k];
        float a3 = As[(ty * 4 + 3) * 68 + k];
        acc[0][0] += a0 * w.x; acc[0][1] += a0 * w.y; acc[0][2] += a0 * w.z; acc[0][3] += a0 * w.w;
        acc[1][0] += a1 * w.x; acc[1][1] += a1 * w.y; acc[1][2] += a1 * w.z; acc[1][3] += a1 * w.w;
        acc[2][0] += a2 * w.x; acc[2][1] += a2 * w.y; acc[2][2] += a2 * w.z; acc[2][3] += a2 * w.w;
        acc[3][0] += a3 * w.x; acc[3][1] += a3 * w.y; acc[3][2] += a3 * w.z; acc[3][3] += a3 * w.w;
      }
    }
    #pragma unroll
    for (int r = 0; r < 4; ++r) {
      int gr = row0 + ty * 4 + r;
      if (gr < M) {
        float4 o = make_float4(fmaxf(acc[r][0] + bv.x, 0.f), fmaxf(acc[r][1] + bv.y, 0.f),
                               fmaxf(acc[r][2] + bv.z, 0.f), fmaxf(acc[r][3] + bv.w, 0.f));
        *(float4*)(C + (size_t)gr * 64 + tx * 4) = o;
      }
    }
  }
}

// ---------------------------------------------------------------------------
// Fused dual GEMM x2 (both node types in one dispatch, grid split):
//   Ga = bf16(A @ Wa) ; Tb = A @ Wb + bias.  Tb may alias A (row-wise safe).
// ---------------------------------------------------------------------------
__global__ __launch_bounds__(256) void gemm_dual2(
    const float* A0, const float* __restrict__ Wa0, const float* __restrict__ Wb0,
    const float* __restrict__ bias0, unsigned short* Ga0, float* Tb0,
    const float* A1, const float* __restrict__ Wa1, const float* __restrict__ Wb1,
    const float* __restrict__ bias1, unsigned short* Ga1, float* Tb1,
    int M, int half_blocks)
{
  __shared__ float Ws[64 * 128];
  __shared__ float As[64 * 68];
  const int tid = threadIdx.x;

  const float* A; const float* Wa; const float* Wb; const float* bias;
  unsigned short* Ga; float* Tb; int t;
  if ((int)blockIdx.x < half_blocks) {
    A = A0; Wa = Wa0; Wb = Wb0; bias = bias0; Ga = Ga0; Tb = Tb0; t = blockIdx.x;
  } else {
    A = A1; Wa = Wa1; Wb = Wb1; bias = bias1; Ga = Ga1; Tb = Tb1; t = blockIdx.x - half_blocks;
  }

  for (int i = tid; i < 2048; i += 256) {
    int k = i >> 5, cg = i & 31;
    float4 v = (cg < 16) ? ((const float4*)Wa)[k * 16 + cg]
                         : ((const float4*)Wb)[k * 16 + (cg - 16)];
    ((float4*)Ws)[k * 32 + cg] = v;
  }

  const int tx = tid & 15;
  const int ty = tid >> 4;
  float4 bvB = ((const float4*)bias)[tx];

  const int row0 = t << 6;
  float accA[4][4] = {};
  float accB[4][4] = {};
  __syncthreads();
  for (int i = tid; i < 1024; i += 256) {
    int r = i >> 4;
    int kk = (i & 15) << 2;
    int gr = row0 + r; if (gr > M - 1) gr = M - 1;
    *(float4*)&As[r * 68 + kk] = *(const float4*)(A + (size_t)gr * 64 + kk);
  }
  __syncthreads();
  #pragma unroll 8
  for (int k = 0; k < 64; ++k) {
    float4 wa = *(const float4*)&Ws[k * 128 + tx * 4];
    float4 wb = *(const float4*)&Ws[k * 128 + 64 + tx * 4];
    float a0 = As[(ty * 4 + 0) * 68 + k];
    float a1 = As[(ty * 4 + 1) * 68 + k];
    float a2 = As[(ty * 4 + 2) * 68 + k];
    float a3 = As[(ty * 4 + 3) * 68 + k];
    accA[0][0] += a0 * wa.x; accA[0][1] += a0 * wa.y; accA[0][2] += a0 * wa.z; accA[0][3] += a0 * wa.w;
    accA[1][0] += a1 * wa.x; accA[1][1] += a1 * wa.y; accA[1][2] += a1 * wa.z; accA[1][3] += a1 * wa.w;
    accA[2][0] += a2 * wa.x; accA[2][1] += a2 * wa.y; accA[2][2] += a2 * wa.z; accA[2][3] += a2 * wa.w;
    accA[3][0] += a3 * wa.x; accA[3][1] += a3 * wa.y; accA[3][2] += a3 * wa.z; accA[3][3] += a3 * wa.w;
    accB[0][0] += a0 * wb.x; accB[0][1] += a0 * wb.y; accB[0][2] += a0 * wb.z; accB[0][3] += a0 * wb.w;
    accB[1][0] += a1 * wb.x; accB[1][1] += a1 * wb.y; accB[1][2] += a1 * wb.z; accB[1][3] += a1 * wb.w;
    accB[2][0] += a2 * wb.x; accB[2][1] += a2 * wb.y; accB[2][2] += a2 * wb.z; accB[2][3] += a2 * wb.w;
    accB[3][0] += a3 * wb.x; accB[3][1] += a3 * wb.y; accB[3][2] += a3 * wb.z; accB[3][3] += a3 * wb.w;
  }
  #pragma unroll
  for (int r = 0; r < 4; ++r) {
    int gr = row0 + ty * 4 + r;
    if (gr < M) {
      ushort4 g;
      g.x = f2bf(accA[r][0]); g.y = f2bf(accA[r][1]);
      g.z = f2bf(accA[r][2]); g.w = f2bf(accA[r][3]);
      *(ushort4*)(Ga + (size_t)gr * 64 + tx * 4) = g;
      *(float4*)(Tb + (size_t)gr * 64 + tx * 4) =
          make_float4(accB[r][0] + bvB.x, accB[r][1] + bvB.y,
                      accB[r][2] + bvB.z, accB[r][3] + bvB.w);
    }
  }
}

// ---------------------------------------------------------------------------
// Fused aggregation x2: out[n,:] = relu(mean_{j in N(n)} bf16 G[j,:] + T[n,:])
// 2 nodes per wave, 2 channels per lane (32-bit gathers).
// ---------------------------------------------------------------------------
__global__ __launch_bounds__(256) void agg2(
    const unsigned short* __restrict__ G0, const float* T0,
    const int* __restrict__ ptr0, const int* __restrict__ idx0, float* out0,
    const unsigned short* __restrict__ G1, const float* T1,
    const int* __restrict__ ptr1, const int* __restrict__ idx1, float* out1,
    int n_dst)
{
  const int lane = threadIdx.x & 63;
  const int sub = lane >> 5;
  const int ch = (lane & 31) << 1;
  int wave = blockIdx.x * 4 + (threadIdx.x >> 6);
  const int nwh = (gridDim.x * 4) >> 1;
  const unsigned short* G; const float* T; const int* ptr; const int* idx; float* out;
  if (wave < nwh) { G = G0; T = T0; ptr = ptr0; idx = idx0; out = out0; }
  else { G = G1; T = T1; ptr = ptr1; idx = idx1; out = out1; wave -= nwh; }

  for (int n0 = wave * 2; n0 < n_dst; n0 += nwh * 2) {
    const int n = n0 + sub;
    const bool valid = n < n_dst;
    const int s = valid ? ptr[n] : 0;
    const int e = valid ? ptr[n + 1] : 0;
    float2 t = make_float2(0.f, 0.f);
    if (valid) t = *(const float2*)(T + (size_t)n * 64 + ch);
    float l0 = 0.f, h0 = 0.f, l1 = 0.f, h1 = 0.f;
    float l2 = 0.f, h2 = 0.f, l3 = 0.f, h3 = 0.f;
    float l4 = 0.f, h4 = 0.f, l5 = 0.f, h5 = 0.f;
    float l6 = 0.f, h6 = 0.f, l7 = 0.f, h7 = 0.f;
    int i = s;
    for (; i + 8 <= e; i += 8) {
      int j0 = __builtin_nontemporal_load(idx + i + 0);
      int j1 = __builtin_nontemporal_load(idx + i + 1);
      int j2 = __builtin_nontemporal_load(idx + i + 2);
      int j3 = __builtin_nontemporal_load(idx + i + 3);
      int j4 = __builtin_nontemporal_load(idx + i + 4);
      int j5 = __builtin_nontemporal_load(idx + i + 5);
      int j6 = __builtin_nontemporal_load(idx + i + 6);
      int j7 = __builtin_nontemporal_load(idx + i + 7);
      unsigned int g0 = *(const unsigned int*)(G + (size_t)j0 * 64 + ch);
      unsigned int g1 = *(const unsigned int*)(G + (size_t)j1 * 64 + ch);
      unsigned int g2 = *(const unsigned int*)(G + (size_t)j2 * 64 + ch);
      unsigned int g3 = *(const unsigned int*)(G + (size_t)j3 * 64 + ch);
      unsigned int g4 = *(const unsigned int*)(G + (size_t)j4 * 64 + ch);
      unsigned int g5 = *(const unsigned int*)(G + (size_t)j5 * 64 + ch);
      unsigned int g6 = *(const unsigned int*)(G + (size_t)j6 * 64 + ch);
      unsigned int g7 = *(const unsigned int*)(G + (size_t)j7 * 64 + ch);
      l0 += bflo(g0); h0 += bfhi(g0); l1 += bflo(g1); h1 += bfhi(g1);
      l2 += bflo(g2); h2 += bfhi(g2); l3 += bflo(g3); h3 += bfhi(g3);
      l4 += bflo(g4); h4 += bfhi(g4); l5 += bflo(g5); h5 += bfhi(g5);
      l6 += bflo(g6); h6 += bfhi(g6); l7 += bflo(g7); h7 += bfhi(g7);
    }
    for (; i < e; ++i) {
      int j = __builtin_nontemporal_load(idx + i);
      unsigned int g = *(const unsigned int*)(G + (size_t)j * 64 + ch);
      l0 += bflo(g); h0 += bfhi(g);
    }
    float sl = ((l0 + l1) + (l2 + l3)) + ((l4 + l5) + (l6 + l7));
    float sh = ((h0 + h1) + (h2 + h3)) + ((h4 + h5) + (h6 + h7));
    int deg = e - s;
    float inv = 1.f / (float)(deg > 0 ? deg : 1);
    if (valid) {
      float2 o = make_float2(fmaxf(sl * inv + t.x, 0.f), fmaxf(sh * inv + t.y, 0.f));
      *(float2*)(out + (size_t)n * 64 + ch) = o;
    }
  }
}

// ---------------------------------------------------------------------------
// CSR build via two-pass counting sort (bucket = dst>>8, 391 buckets/type).
// ---------------------------------------------------------------------------
// K0: global bucket histogram (LDS hist, one flush per block).
__global__ __launch_bounds__(256) void bucket_hist(
    const int* __restrict__ dstA, const int* __restrict__ dstB,
    int* histA, int* histB, int E)
{
  __shared__ int h[NBKT];
  for (int i = threadIdx.x; i < NBKT; i += 256) h[i] = 0;
  __syncthreads();
  const int half = gridDim.x >> 1;
  const bool isB = (int)blockIdx.x >= half;
  const int* dst = isB ? dstB : dstA;
  int* hist = isB ? histB : histA;
  const int b0 = isB ? blockIdx.x - half : blockIdx.x;
  for (int e = b0 * 256 + (int)threadIdx.x; e < E; e += half * 256)
    atomicAdd(&h[__builtin_nontemporal_load(dst + e) >> 8], 1);
  __syncthreads();
  for (int i = threadIdx.x; i < NBKT; i += 256)
    if (h[i]) atomicAdd(&hist[i], h[i]);
}

// K1: scan bucket counts -> bases (read-only for K3) + cursors (consumed by
// K2); also publishes ptr[N] = E for both types.
__global__ __launch_bounds__(512) void bucket_scan(
    const int* __restrict__ histA, const int* __restrict__ histB,
    int* baseA, int* curA, int* baseB, int* curB,
    int* ptrA_end, int* ptrB_end, int E)
{
  __shared__ int sA[512], sB[512];
  const int t = threadIdx.x;
  int vA = (t < NBKT) ? histA[t] : 0;
  int vB = (t < NBKT) ? histB[t] : 0;
  sA[t] = vA; sB[t] = vB;
  __syncthreads();
  for (int off = 1; off < 512; off <<= 1) {
    int xA = 0, xB = 0;
    if (t >= off) { xA = sA[t - off]; xB = sB[t - off]; }
    __syncthreads();
    if (t >= off) { sA[t] += xA; sB[t] += xB; }
    __syncthreads();
  }
  if (t < NBKT) {
    int eA = sA[t] - vA, eB = sB[t] - vB;
    baseA[t] = eA; curA[t] = eA;
    baseB[t] = eB; curB[t] = eB;
  }
  if (t == 0) {
    baseA[NBKT] = E; baseB[NBKT] = E;
    *ptrA_end = E; *ptrB_end = E;
  }
}

// K2: partition edges into bucket-contiguous packed entries.
// pack = (dst&255)<<24 | src  (src < 2^17 fits in 24 bits).
// Per-chunk runs are reserved with ONE global atomic per (chunk,bucket);
// scatter positions come from LDS cursor atomics -> contiguous ~84B runs.
__global__ __launch_bounds__(256) void partition2(
    const int* __restrict__ srcA, const int* __restrict__ dstA, int* curA, unsigned int* pairsA,
    const int* __restrict__ srcB, const int* __restrict__ dstB, int* curB, unsigned int* pairsB,
    int E)
{
  __shared__ int h[NBKT];
  __shared__ int c[NBKT];
  const int half = gridDim.x >> 1;   // chunks per type
  const bool isB = (int)blockIdx.x >= half;
  const int chunk = isB ? blockIdx.x - half : blockIdx.x;
  const int* src = isB ? srcB : srcA;
  const int* dst = isB ? dstB : dstA;
  int* cur = isB ? curB : curA;
  unsigned int* pairs = isB ? pairsB : pairsA;
  const int e0 = chunk * ACHUNK;
  const int e1 = min(e0 + ACHUNK, E);
  for (int i = threadIdx.x; i < NBKT; i += 256) h[i] = 0;
  __syncthreads();
  for (int e = e0 + (int)threadIdx.x; e < e1; e += 256)
    atomicAdd(&h[__builtin_nontemporal_load(dst + e) >> 8], 1);
  __syncthreads();
  for (int i = threadIdx.x; i < NBKT; i += 256) {
    int v = h[i];
    if (v) c[i] = atomicAdd(&cur[i], v);
  }
  __syncthreads();
  for (int e = e0 + (int)threadIdx.x; e < e1; e += 256) {
    int d = __builtin_nontemporal_load(dst + e);
    int s = __builtin_nontemporal_load(src + e);
    int b = d >> 8;
    int p = atomicAdd(&c[b], 1);
    pairs[p] = ((unsigned int)(d & 255) << 24) | (unsigned int)s;
  }
}

// K3: per-bucket CSR finalize: degree hist (LDS) -> scan (LDS) -> ptr write
// (coalesced) -> scatter src into the bucket's own ~16KB idx region using
// LDS cursors. Single workgroup owns each region: confined, full-line writes.
__global__ __launch_bounds__(256) void bucket_fill(
    const unsigned int* __restrict__ pairsA, const int* __restrict__ baseA,
    int* __restrict__ ptrA, int* __restrict__ idxA,
    const unsigned int* __restrict__ pairsB, const int* __restrict__ baseB,
    int* __restrict__ ptrB, int* __restrict__ idxB, int n)
{
  __shared__ int h[NPB];
  __shared__ int cur[NPB];
  const bool isB = (int)blockIdx.x >= NBKT;
  const int b = isB ? blockIdx.x - NBKT : blockIdx.x;
  const unsigned int* pairs = isB ? pairsB : pairsA;
  const int* base = isB ? baseB : baseA;
  int* ptr = isB ? ptrB : ptrA;
  int* idx = isB ? idxB : idxA;
  const int ebase = base[b];
  const int eend = base[b + 1];
  const int t = threadIdx.x;
  h[t] = 0;
  __syncthreads();
  for (int e = ebase + t; e < eend; e += 256)
    atomicAdd(&h[pairs[e] >> 24], 1);
  __syncthreads();
  const int v = h[t];
  __syncthreads();
  for (int off = 1; off < 256; off <<= 1) {
    int x = 0;
    if (t >= off) x = h[t - off];
    __syncthreads();
    if (t >= off) h[t] += x;
    __syncthreads();
  }
  const int excl = h[t] - v;
  const int gnode = b * NPB + t;
  if (gnode < n) ptr[gnode] = ebase + excl;
  cur[t] = excl;
  __syncthreads();
  for (int e = ebase + t; e < eend; e += 256) {
    unsigned int pk = pairs[e];
    int p = atomicAdd(&cur[pk >> 24], 1);
    idx[ebase + p] = (int)(pk & 0xFFFFFFu);
  }
}

// ---------------------------------------------------------------------------
extern "C" void kernel_launch(void* const* d_in, const int* in_sizes, int n_in,
                              void* d_out, int out_size, void* d_ws, size_t ws_size,
                              hipStream_t stream) {
  const float* x_user = (const float*)d_in[0];
  const float* x_item = (const float*)d_in[1];
  const int*   edge_ui = (const int*)d_in[2];   // A: dst = item
  const int*   edge_iu = (const int*)d_in[3];   // B: dst = user
  const float* Wu = (const float*)d_in[4];
  const float* bu = (const float*)d_in[5];
  const float* Wi = (const float*)d_in[6];
  const float* bi = (const float*)d_in[7];
  const float* Wl = (const float*)d_in[8];
  const float* bl = (const float*)d_in[9];
  const float* Wr = (const float*)d_in[10];

  float* outU = (float*)d_out;
  float* outI = outU + (size_t)NUSER * HID;

  char* p = (char*)d_ws;
  auto alloc = [&](size_t bytes) -> void* {
    void* r = (void*)p; p += (bytes + 255) & ~(size_t)255; return r;
  };
  float* U = (float*)alloc((size_t)NUSER * HID * 4);          // hu0
  float* I = (float*)alloc((size_t)NITEM * HID * 4);          // hi0
  unsigned short* GA = (unsigned short*)alloc((size_t)NUSER * HID * 2);
  unsigned short* GB = (unsigned short*)alloc((size_t)NITEM * HID * 2);
  // pairs buffers alias GA/GB: dead before the first gemm_dual2 writes GA/GB.
  unsigned int* pairsA = (unsigned int*)GA;   // 6.4 MB (E * 4B)
  unsigned int* pairsB = pairsA + NEDGE;      // 6.4 MB (GA+GB carve = 25.6 MB total)
  // bucket metadata: ONE carve; memset covers exactly the leading hist region
  // (r3 lesson: never memset across separately-padded carves).
  int* histA = (int*)alloc((size_t)(2 * NBKT + 2 * (NBKT + 1) + 2 * NBKT) * 4);
  int* histB = histA + NBKT;
  int* baseA = histB + NBKT;          // NBKT+1
  int* baseB = baseA + NBKT + 1;      // NBKT+1
  int* curA  = baseB + NBKT + 1;
  int* curB  = curA + NBKT;
  int* ptr_ui = (int*)alloc(((size_t)NITEM + 1) * 4);
  int* ptr_iu = (int*)alloc(((size_t)NUSER + 1) * 4);
  int* idx_ui = (int*)alloc((size_t)NEDGE * 4);
  int* idx_iu = (int*)alloc((size_t)NEDGE * 4);

  // ---- CSR build: counting sort (memset + 4 dispatches) ----
  hipMemsetAsync(histA, 0, (size_t)(2 * NBKT) * 4, stream);
  bucket_hist<<<784, 256, 0, stream>>>(edge_ui + NEDGE, edge_iu + NEDGE,
                                       histA, histB, NEDGE);
  bucket_scan<<<1, 512, 0, stream>>>(histA, histB, baseA, curA, baseB, curB,
                                     ptr_ui + NITEM, ptr_iu + NUSER, NEDGE);
  partition2<<<2 * NCHUNK, 256, 0, stream>>>(
      edge_ui, edge_ui + NEDGE, curA, pairsA,
      edge_iu, edge_iu + NEDGE, curB, pairsB, NEDGE);
  bucket_fill<<<2 * NBKT, 256, 0, stream>>>(pairsA, baseA, ptr_ui, idx_ui,
                                            pairsB, baseB, ptr_iu, idx_iu, NITEM);

  const int GT = (NUSER + 63) / 64;            // 1563
  const int AGG_B = 2 * ((NUSER / 2 + 3) / 4); // 25000

  const float* Wl00 = Wl;             const float* Wl01 = Wl + 4096;
  const float* Wl10 = Wl + 2 * 4096;  const float* Wl11 = Wl + 3 * 4096;
  const float* Wr00 = Wr;             const float* Wr01 = Wr + 4096;
  const float* Wr10 = Wr + 2 * 4096;  const float* Wr11 = Wr + 3 * 4096;
  const float* bl00 = bl;             const float* bl01 = bl + 64;
  const float* bl10 = bl + 128;       const float* bl11 = bl + 192;

  // ---- input linears ----
  gemm64<128><<<GT, 256, 0, stream>>>(x_user, Wu, bu, U, NUSER);  // hu0
  gemm64<64 ><<<GT, 256, 0, stream>>>(x_item, Wi, bi, I, NITEM);  // hi0

  // ---- layer 0 ----
  gemm_dual2<<<2 * GT, 256, 0, stream>>>(U, Wl00, Wr01, bl01, GA, outU,
                                         I, Wl01, Wr00, bl00, GB, outI,
                                         NUSER, GT);
  agg2<<<AGG_B, 256, 0, stream>>>(GA, outI, ptr_ui, idx_ui, outI,
                                  GB, outU, ptr_iu, idx_iu, outU, NITEM);

  // ---- layer 1 ----
  gemm_dual2<<<2 * GT, 256, 0, stream>>>(outI, Wl11, Wr10, bl10, GA, outI,
                                         outU, Wl10, Wr11, bl11, GB, outU,
                                         NITEM, GT);
  agg2<<<AGG_B, 256, 0, stream>>>(GA, outU, ptr_iu, idx_iu, outU,
                                  GB, outI, ptr_ui, idx_ui, outI, NUSER);
}